// Round 4
// baseline (522.342 us; speedup 1.0000x reference)
//
#include <hip/hip_runtime.h>

// Problem constants (fixed by setup_inputs): B=32, L=1024, K=64, N=8
namespace {
constexpr int Bb = 32, Ll = 1024, Kk = 64, Nn = 8;
constexpr int BLK = Bb * Ll * Kk;                      // 2,097,152 (b,l,k) elements
constexpr long long HFLOATS = (long long)BLK * Nn * 2; // 33,554,432 floats in H
constexpr int CH = 16;                                  // avg-reduction chunks per b
constexpr int LCH = Ll / CH;                            // 64 l's per chunk

// Output layout (flat concatenation in reference return order)
constexpr long long OFF_VQ  = 0;                         // v_q: BLK*2
constexpr long long OFF_HQ  = (long long)BLK * 2;        // H_q: BLK*16
constexpr long long OFF_EBD = OFF_HQ + HFLOATS;          // expected_bits_demod: BLK
constexpr long long OFF_EBC = OFF_EBD + BLK;             // expected_bits_channel: BLK
constexpr long long OFF_WD  = OFF_EBC + BLK;             // w_demod: BLK*3
constexpr long long OFF_WC  = OFF_WD + (long long)BLK*3; // w_channel: BLK*3
} // namespace

// forward of _lsq with precomputed reciprocal: round(clip(x*inv, Qn, Qp)) * s
__device__ __forceinline__ float lsq_i(float x, float inv, float s, float Qn, float Qp) {
    float xc = fminf(fmaxf(x * inv, Qn), Qp);
    return rintf(xc) * s;   // rintf = round-half-even, matches jnp.round
}

// w = hard_onehot(argmax(z)) + y - stopgrad(y), computed literally as (hard + y) - y.
// __expf + single-reciprocal softmax: deviation ~1e-7 in w (threshold 1.28; R3 absmax 9e-7).
__device__ __forceinline__ void hard_gumbel(float z0, float z1, float z2, float w[3]) {
    int arg = 0; float m = z0;
    if (z1 > m) { m = z1; arg = 1; }   // strict > : first-occurrence tie-break = jnp.argmax
    if (z2 > m) { m = z2; arg = 2; }
    float e0 = __expf(z0 - m), e1 = __expf(z1 - m), e2 = __expf(z2 - m);
    float r  = 1.0f / (e0 + e1 + e2);
    float y0 = e0 * r, y1 = e1 * r, y2 = e2 * r;
    w[0] = ((arg == 0 ? 1.0f : 0.0f) + y0) - y0;
    w[1] = ((arg == 1 ? 1.0f : 0.0f) + y1) - y1;
    w[2] = ((arg == 2 ? 1.0f : 0.0f) + y2) - y2;
}

// ---------------------------------------------------------------------------
// Kernel 1: chunked h_power sums for avg.  partial[b][c][k] = sum_{l in chunk c}
// (f32)(f64 sum_{n,cx} H^2), accumulated in f64, deterministic order.
// grid = Bb*CH = 512 blocks x 256 threads; float4 loads cover a k-pair. HBM-bound.
__global__ __launch_bounds__(256) void hpa_kernel(const float* __restrict__ H,
                                                  double* __restrict__ partial) {
    int blk = blockIdx.x;            // b*CH + c
    int b   = blk >> 4;
    int c   = blk & (CH - 1);
    int t   = threadIdx.x;
    int kp  = t & 31;                // k-pair index (k = 2*kp, 2*kp+1)
    int ls  = t >> 5;                // 8 l-lanes
    const float4* Hf = (const float4*)H;   // layout: [(bl*Nn + n)*32 + kp]
    double acc0 = 0.0, acc1 = 0.0;
    int l0 = c * LCH + ls;
    for (int i = 0; i < LCH / 8; ++i) {              // 8 l's per thread, stride 8
        int l = l0 + i * 8;
        const float4* Hb = Hf + (long long)(b * Ll + l) * (Nn * 32) + kp;
        double e0 = 0.0, e1 = 0.0;
        #pragma unroll
        for (int n = 0; n < Nn; ++n) {
            float4 h = Hb[n * 32];
            e0 += (double)(h.x * h.x);   // f32-rounded squares (match np H*H)
            e0 += (double)(h.y * h.y);
            e1 += (double)(h.z * h.z);
            e1 += (double)(h.w * h.w);
        }
        acc0 += (double)(float)e0;       // hp value f32-rounded exactly as np sees it
        acc1 += (double)(float)e1;
    }
    __shared__ double sh[2][256];
    sh[0][t] = acc0;
    sh[1][t] = acc1;
    __syncthreads();
    if (t < 64) {
        int kp2 = t & 31, sel = t >> 5;
        double s = 0.0;
        #pragma unroll
        for (int l2 = 0; l2 < 8; ++l2) s += sh[sel][l2 * 32 + kp2];
        partial[(long long)blk * 64 + 2 * kp2 + sel] = s;   // = partial[b][c][k]
    }
}

// ---------------------------------------------------------------------------
// Kernel 2: everything else, fused. ONE element (b,l,k) per thread (R2 winner).
// Occupancy-first: streaming h1 (no h1[] array), H reloaded for the epilogue,
// avg finalize deduped to 64 threads/block via LDS. Target <=64 VGPR, 8 waves/SIMD.
__global__ __launch_bounds__(256, 8) void fused_kernel(
    const float* __restrict__ v,  const float* __restrict__ snr,
    const float* __restrict__ gd, const float* __restrict__ gc,
    const float* __restrict__ W1, const float* __restrict__ b1,
    const float* __restrict__ W2, const float* __restrict__ b2,
    const float* __restrict__ Wd, const float* __restrict__ bd,
    const float* __restrict__ Wc, const float* __restrict__ bc,
    const float* __restrict__ ps2d, const float* __restrict__ ps4d,
    const float* __restrict__ ps2c, const float* __restrict__ ps4c,
    const double* __restrict__ partial,
    const float* __restrict__ H,
    float* __restrict__ out) {
    int idx = blockIdx.x * 256 + threadIdx.x;
    int t   = threadIdx.x;
    int b   = idx >> 16;     // L*K = 65536 (uniform per block)
    int k   = idx & 63;
    int bl  = idx >> 6;      // b*L + l

    // ---- avg finalize, deduped: 64 threads sum the 16 f64 chunk partials for
    // their k (same order as before: c = 0..15 sequential), broadcast via LDS.
    __shared__ float avg_sh[64];
    if (t < 64) {
        const double* pb = partial + (long long)b * (CH * 64) + t;
        double s = 0.0;
        #pragma unroll
        for (int c = 0; c < CH; ++c) s += pb[c * 64];
        avg_sh[t] = (float)(s * (1.0 / 1024.0));
    }

    // ---- h_power: load H fragment, square-accumulate in f64, regs freed after
    const float2* Hf = (const float2*)H + (long long)bl * (Nn * Kk) + k;
    double hacc = 0.0;
    #pragma unroll
    for (int n = 0; n < Nn; ++n) {
        float2 h = Hf[n * Kk];
        hacc += (double)(h.x * h.x);
        hacc += (double)(h.y * h.y);
    }
    float p3 = (float)hacc;

    __syncthreads();
    float p4 = avg_sh[k];

    float2 vv = ((const float2*)v)[idx];
    float p0 = vv.x, p1 = vv.y;
    float p2 = snr[idx];

    // ---- MLP: layer 1 streamed into layer 2 (no h1 array; small live set)
    float h2[32];
    #pragma unroll
    for (int i = 0; i < 32; ++i) h2[i] = b2[i];
    #pragma unroll
    for (int j = 0; j < 32; ++j) {
        float a = b1[j];
        a = fmaf(p0, W1[j],       a);
        a = fmaf(p1, W1[32 + j],  a);
        a = fmaf(p2, W1[64 + j],  a);
        a = fmaf(p3, W1[96 + j],  a);
        a = fmaf(p4, W1[128 + j], a);
        float hj = fmaxf(a, 0.0f);
        #pragma unroll
        for (int i = 0; i < 32; ++i) h2[i] = fmaf(hj, W2[j * 32 + i], h2[i]);
    }
    // ---- heads: relu(h2) streamed into 6 logit accumulators
    float ld0 = bd[0], ld1 = bd[1], ld2 = bd[2];
    float lc0 = bc[0], lc1 = bc[1], lc2 = bc[2];
    #pragma unroll
    for (int j = 0; j < 32; ++j) {
        float hj = fmaxf(h2[j], 0.0f);
        ld0 = fmaf(hj, Wd[j * 3 + 0], ld0);
        ld1 = fmaf(hj, Wd[j * 3 + 1], ld1);
        ld2 = fmaf(hj, Wd[j * 3 + 2], ld2);
        lc0 = fmaf(hj, Wc[j * 3 + 0], lc0);
        lc1 = fmaf(hj, Wc[j * 3 + 1], lc1);
        lc2 = fmaf(hj, Wc[j * 3 + 2], lc2);
    }

    long long i3 = (long long)idx * 3;
    float wdm[3], wch[3];
    hard_gumbel(ld0 + gd[i3], ld1 + gd[i3 + 1], ld2 + gd[i3 + 2], wdm);  // tau=1
    hard_gumbel(lc0 + gc[i3], lc1 + gc[i3 + 1], lc2 + gc[i3 + 2], wch);

    // ---- scales + reciprocals (s=0.5 exact; s=0.1 wobble <= one step << 1.28)
    float s2d = *ps2d, s4d = *ps4d, s2c = *ps2c, s4c = *ps4c;
    float i2d = 1.0f / s2d, i4d = 1.0f / s4d, i2c = 1.0f / s2c, i4c = 1.0f / s4c;

    // ---- v_q
    float q0 = wdm[1] * lsq_i(p0, i2d, s2d, -2.0f, 1.0f)
             + wdm[2] * lsq_i(p0, i4d, s4d, -8.0f, 7.0f);
    float q1 = wdm[1] * lsq_i(p1, i2d, s2d, -2.0f, 1.0f)
             + wdm[2] * lsq_i(p1, i4d, s4d, -8.0f, 7.0f);
    ((float2*)(out + OFF_VQ))[idx] = make_float2(q0, q1);

    // ---- bits + gate outputs
    out[OFF_EBD + idx] = wdm[1] * 4.0f + wdm[2] * 8.0f;
    out[OFF_EBC + idx] = wch[1] * 32.0f + wch[2] * 64.0f;  // 2*N*2, 2*N*4 (N=8)
    out[OFF_WD + i3 + 0] = wdm[0];
    out[OFF_WD + i3 + 1] = wdm[1];
    out[OFF_WD + i3 + 2] = wdm[2];
    out[OFF_WC + i3 + 0] = wch[0];
    out[OFF_WC + i3 + 1] = wch[1];
    out[OFF_WC + i3 + 2] = wch[2];

    // ---- H_q epilogue: re-load H (L2/L3-warm; kept MLP-phase VGPRs low)
    float w1c = wch[1], w2c = wch[2];
    float2* outHQ = (float2*)(out + OFF_HQ) + (long long)bl * (Nn * Kk) + k;
    #pragma unroll
    for (int n = 0; n < Nn; ++n) {
        float2 h = Hf[n * Kk];
        float qx = w1c * lsq_i(h.x, i2c, s2c, -2.0f, 1.0f)
                 + w2c * lsq_i(h.x, i4c, s4c, -8.0f, 7.0f);
        float qy = w1c * lsq_i(h.y, i2c, s2c, -2.0f, 1.0f)
                 + w2c * lsq_i(h.y, i4c, s4c, -8.0f, 7.0f);
        outHQ[n * Kk] = make_float2(qx, qy);
    }
}

// ---------------------------------------------------------------------------
extern "C" void kernel_launch(void* const* d_in, const int* in_sizes, int n_in,
                              void* d_out, int out_size, void* d_ws, size_t ws_size,
                              hipStream_t stream) {
    const float* v    = (const float*)d_in[0];
    const float* H    = (const float*)d_in[1];
    const float* snr  = (const float*)d_in[2];
    const float* gd   = (const float*)d_in[3];
    const float* gc   = (const float*)d_in[4];
    const float* W1   = (const float*)d_in[5];
    const float* b1   = (const float*)d_in[6];
    const float* W2   = (const float*)d_in[7];
    const float* b2   = (const float*)d_in[8];
    const float* Wd   = (const float*)d_in[9];
    const float* bd   = (const float*)d_in[10];
    const float* Wc   = (const float*)d_in[11];
    const float* bc   = (const float*)d_in[12];
    const float* s2d  = (const float*)d_in[13];
    const float* s4d  = (const float*)d_in[14];
    const float* s2c  = (const float*)d_in[15];
    const float* s4c  = (const float*)d_in[16];

    float* out = (float*)d_out;
    double* partial = (double*)d_ws;   // Bb*CH*64 doubles = 256 KB, fully written by k1

    hpa_kernel<<<Bb * CH, 256, 0, stream>>>(H, partial);
    fused_kernel<<<BLK / 256, 256, 0, stream>>>(v, snr, gd, gc, W1, b1, W2, b2,
                                                Wd, bd, Wc, bc, s2d, s4d, s2c, s4c,
                                                partial, H, out);
}

// Round 5
// 447.425 us; speedup vs baseline: 1.1674x; 1.1674x over previous
//
#include <hip/hip_runtime.h>

// Problem constants (fixed by setup_inputs): B=32, L=1024, K=64, N=8
namespace {
constexpr int Bb = 32, Ll = 1024, Kk = 64, Nn = 8;
constexpr int BLK = Bb * Ll * Kk;                      // 2,097,152 (b,l,k) elements
constexpr long long HFLOATS = (long long)BLK * Nn * 2; // 33,554,432 floats in H
constexpr int CH = 16;                                  // avg-reduction chunks per b
constexpr int LCH = Ll / CH;                            // 64 l's per chunk

// Output layout (flat concatenation in reference return order)
constexpr long long OFF_VQ  = 0;                         // v_q: BLK*2
constexpr long long OFF_HQ  = (long long)BLK * 2;        // H_q: BLK*16
constexpr long long OFF_EBD = OFF_HQ + HFLOATS;          // expected_bits_demod: BLK
constexpr long long OFF_EBC = OFF_EBD + BLK;             // expected_bits_channel: BLK
constexpr long long OFF_WD  = OFF_EBC + BLK;             // w_demod: BLK*3
constexpr long long OFF_WC  = OFF_WD + (long long)BLK*3; // w_channel: BLK*3
} // namespace

// forward of _lsq with precomputed reciprocal: round(clip(x*inv, Qn, Qp)) * s
__device__ __forceinline__ float lsq_i(float x, float inv, float s, float Qn, float Qp) {
    float xc = fminf(fmaxf(x * inv, Qn), Qp);
    return rintf(xc) * s;   // rintf = round-half-even, matches jnp.round
}

// w = hard_onehot(argmax(z)) + y - stopgrad(y), computed literally as (hard + y) - y.
// __expf + single-reciprocal softmax: deviation ~1e-7 in w (threshold 1.28; absmax 9e-7).
__device__ __forceinline__ void hard_gumbel(float z0, float z1, float z2, float w[3]) {
    int arg = 0; float m = z0;
    if (z1 > m) { m = z1; arg = 1; }   // strict > : first-occurrence tie-break = jnp.argmax
    if (z2 > m) { m = z2; arg = 2; }
    float e0 = __expf(z0 - m), e1 = __expf(z1 - m), e2 = __expf(z2 - m);
    float r  = 1.0f / (e0 + e1 + e2);
    float y0 = e0 * r, y1 = e1 * r, y2 = e2 * r;
    w[0] = ((arg == 0 ? 1.0f : 0.0f) + y0) - y0;
    w[1] = ((arg == 1 ? 1.0f : 0.0f) + y1) - y1;
    w[2] = ((arg == 2 ? 1.0f : 0.0f) + y2) - y2;
}

// ---------------------------------------------------------------------------
// Kernel 1: chunked h_power sums for avg.  partial[b][c][k] = sum_{l in chunk c}
// (f32)(f64 sum_{n,cx} H^2), accumulated in f64, deterministic order.
// grid = Bb*CH = 512 blocks x 256 threads; float4 loads cover a k-pair. HBM-bound.
__global__ __launch_bounds__(256) void hpa_kernel(const float* __restrict__ H,
                                                  double* __restrict__ partial) {
    int blk = blockIdx.x;            // b*CH + c
    int b   = blk >> 4;
    int c   = blk & (CH - 1);
    int t   = threadIdx.x;
    int kp  = t & 31;                // k-pair index (k = 2*kp, 2*kp+1)
    int ls  = t >> 5;                // 8 l-lanes
    const float4* Hf = (const float4*)H;   // layout: [(bl*Nn + n)*32 + kp]
    double acc0 = 0.0, acc1 = 0.0;
    int l0 = c * LCH + ls;
    for (int i = 0; i < LCH / 8; ++i) {              // 8 l's per thread, stride 8
        int l = l0 + i * 8;
        const float4* Hb = Hf + (long long)(b * Ll + l) * (Nn * 32) + kp;
        double e0 = 0.0, e1 = 0.0;
        #pragma unroll
        for (int n = 0; n < Nn; ++n) {
            float4 h = Hb[n * 32];
            e0 += (double)(h.x * h.x);   // f32-rounded squares (match np H*H)
            e0 += (double)(h.y * h.y);
            e1 += (double)(h.z * h.z);
            e1 += (double)(h.w * h.w);
        }
        acc0 += (double)(float)e0;       // hp value f32-rounded exactly as np sees it
        acc1 += (double)(float)e1;
    }
    __shared__ double sh[2][256];
    sh[0][t] = acc0;
    sh[1][t] = acc1;
    __syncthreads();
    if (t < 64) {
        int kp2 = t & 31, sel = t >> 5;
        double s = 0.0;
        #pragma unroll
        for (int l2 = 0; l2 < 8; ++l2) s += sh[sel][l2 * 32 + kp2];
        partial[(long long)blk * 64 + 2 * kp2 + sel] = s;   // = partial[b][c][k]
    }
}

// ---------------------------------------------------------------------------
// Kernel 2: everything else, fused. ONE element (b,l,k) per thread.
// R4 structure (streamed h1, H reloaded for epilogue, LDS-deduped avg) but with
// NO register cap: __launch_bounds__(256,8) forced VGPR=32 -> scratch spills
// (FETCH 103->185 MB, fused 145->209 us). Natural allocation ~56-64 VGPR is
// spill-free and still reaches ~8 waves/SIMD.
__global__ __launch_bounds__(256) void fused_kernel(
    const float* __restrict__ v,  const float* __restrict__ snr,
    const float* __restrict__ gd, const float* __restrict__ gc,
    const float* __restrict__ W1, const float* __restrict__ b1,
    const float* __restrict__ W2, const float* __restrict__ b2,
    const float* __restrict__ Wd, const float* __restrict__ bd,
    const float* __restrict__ Wc, const float* __restrict__ bc,
    const float* __restrict__ ps2d, const float* __restrict__ ps4d,
    const float* __restrict__ ps2c, const float* __restrict__ ps4c,
    const double* __restrict__ partial,
    const float* __restrict__ H,
    float* __restrict__ out) {
    int idx = blockIdx.x * 256 + threadIdx.x;
    int t   = threadIdx.x;
    int b   = idx >> 16;     // L*K = 65536 (uniform per block)
    int k   = idx & 63;
    int bl  = idx >> 6;      // b*L + l

    // ---- avg finalize, deduped: 64 threads sum the 16 f64 chunk partials for
    // their k (same order as before: c = 0..15 sequential), broadcast via LDS.
    __shared__ float avg_sh[64];
    if (t < 64) {
        const double* pb = partial + (long long)b * (CH * 64) + t;
        double s = 0.0;
        #pragma unroll
        for (int c = 0; c < CH; ++c) s += pb[c * 64];
        avg_sh[t] = (float)(s * (1.0 / 1024.0));
    }

    // ---- h_power: load H fragment, square-accumulate in f64, regs freed after
    const float2* Hf = (const float2*)H + (long long)bl * (Nn * Kk) + k;
    double hacc = 0.0;
    #pragma unroll
    for (int n = 0; n < Nn; ++n) {
        float2 h = Hf[n * Kk];
        hacc += (double)(h.x * h.x);
        hacc += (double)(h.y * h.y);
    }
    float p3 = (float)hacc;

    __syncthreads();
    float p4 = avg_sh[k];

    float2 vv = ((const float2*)v)[idx];
    float p0 = vv.x, p1 = vv.y;
    float p2 = snr[idx];

    // ---- MLP: layer 1 streamed into layer 2 (no h1 array; small live set)
    float h2[32];
    #pragma unroll
    for (int i = 0; i < 32; ++i) h2[i] = b2[i];
    #pragma unroll
    for (int j = 0; j < 32; ++j) {
        float a = b1[j];
        a = fmaf(p0, W1[j],       a);
        a = fmaf(p1, W1[32 + j],  a);
        a = fmaf(p2, W1[64 + j],  a);
        a = fmaf(p3, W1[96 + j],  a);
        a = fmaf(p4, W1[128 + j], a);
        float hj = fmaxf(a, 0.0f);
        #pragma unroll
        for (int i = 0; i < 32; ++i) h2[i] = fmaf(hj, W2[j * 32 + i], h2[i]);
    }
    // ---- heads: relu(h2) streamed into 6 logit accumulators
    float ld0 = bd[0], ld1 = bd[1], ld2 = bd[2];
    float lc0 = bc[0], lc1 = bc[1], lc2 = bc[2];
    #pragma unroll
    for (int j = 0; j < 32; ++j) {
        float hj = fmaxf(h2[j], 0.0f);
        ld0 = fmaf(hj, Wd[j * 3 + 0], ld0);
        ld1 = fmaf(hj, Wd[j * 3 + 1], ld1);
        ld2 = fmaf(hj, Wd[j * 3 + 2], ld2);
        lc0 = fmaf(hj, Wc[j * 3 + 0], lc0);
        lc1 = fmaf(hj, Wc[j * 3 + 1], lc1);
        lc2 = fmaf(hj, Wc[j * 3 + 2], lc2);
    }

    long long i3 = (long long)idx * 3;
    float wdm[3], wch[3];
    hard_gumbel(ld0 + gd[i3], ld1 + gd[i3 + 1], ld2 + gd[i3 + 2], wdm);  // tau=1
    hard_gumbel(lc0 + gc[i3], lc1 + gc[i3 + 1], lc2 + gc[i3 + 2], wch);

    // ---- scales + reciprocals (s=0.5 exact; s=0.1 wobble <= one step << 1.28)
    float s2d = *ps2d, s4d = *ps4d, s2c = *ps2c, s4c = *ps4c;
    float i2d = 1.0f / s2d, i4d = 1.0f / s4d, i2c = 1.0f / s2c, i4c = 1.0f / s4c;

    // ---- v_q
    float q0 = wdm[1] * lsq_i(p0, i2d, s2d, -2.0f, 1.0f)
             + wdm[2] * lsq_i(p0, i4d, s4d, -8.0f, 7.0f);
    float q1 = wdm[1] * lsq_i(p1, i2d, s2d, -2.0f, 1.0f)
             + wdm[2] * lsq_i(p1, i4d, s4d, -8.0f, 7.0f);
    ((float2*)(out + OFF_VQ))[idx] = make_float2(q0, q1);

    // ---- bits + gate outputs
    out[OFF_EBD + idx] = wdm[1] * 4.0f + wdm[2] * 8.0f;
    out[OFF_EBC + idx] = wch[1] * 32.0f + wch[2] * 64.0f;  // 2*N*2, 2*N*4 (N=8)
    out[OFF_WD + i3 + 0] = wdm[0];
    out[OFF_WD + i3 + 1] = wdm[1];
    out[OFF_WD + i3 + 2] = wdm[2];
    out[OFF_WC + i3 + 0] = wch[0];
    out[OFF_WC + i3 + 1] = wch[1];
    out[OFF_WC + i3 + 2] = wch[2];

    // ---- H_q epilogue: re-load H (L2/L3-warm; kept MLP-phase VGPRs low)
    float w1c = wch[1], w2c = wch[2];
    float2* outHQ = (float2*)(out + OFF_HQ) + (long long)bl * (Nn * Kk) + k;
    #pragma unroll
    for (int n = 0; n < Nn; ++n) {
        float2 h = Hf[n * Kk];
        float qx = w1c * lsq_i(h.x, i2c, s2c, -2.0f, 1.0f)
                 + w2c * lsq_i(h.x, i4c, s4c, -8.0f, 7.0f);
        float qy = w1c * lsq_i(h.y, i2c, s2c, -2.0f, 1.0f)
                 + w2c * lsq_i(h.y, i4c, s4c, -8.0f, 7.0f);
        outHQ[n * Kk] = make_float2(qx, qy);
    }
}

// ---------------------------------------------------------------------------
extern "C" void kernel_launch(void* const* d_in, const int* in_sizes, int n_in,
                              void* d_out, int out_size, void* d_ws, size_t ws_size,
                              hipStream_t stream) {
    const float* v    = (const float*)d_in[0];
    const float* H    = (const float*)d_in[1];
    const float* snr  = (const float*)d_in[2];
    const float* gd   = (const float*)d_in[3];
    const float* gc   = (const float*)d_in[4];
    const float* W1   = (const float*)d_in[5];
    const float* b1   = (const float*)d_in[6];
    const float* W2   = (const float*)d_in[7];
    const float* b2   = (const float*)d_in[8];
    const float* Wd   = (const float*)d_in[9];
    const float* bd   = (const float*)d_in[10];
    const float* Wc   = (const float*)d_in[11];
    const float* bc   = (const float*)d_in[12];
    const float* s2d  = (const float*)d_in[13];
    const float* s4d  = (const float*)d_in[14];
    const float* s2c  = (const float*)d_in[15];
    const float* s4c  = (const float*)d_in[16];

    float* out = (float*)d_out;
    double* partial = (double*)d_ws;   // Bb*CH*64 doubles = 256 KB, fully written by k1

    hpa_kernel<<<Bb * CH, 256, 0, stream>>>(H, partial);
    fused_kernel<<<BLK / 256, 256, 0, stream>>>(v, snr, gd, gc, W1, b1, W2, b2,
                                                Wd, bd, Wc, bc, s2d, s4d, s2c, s4c,
                                                partial, H, out);
}